// Round 6
// baseline (149.631 us; speedup 1.0000x reference)
//
#include <hip/hip_runtime.h>
#include <hip/hip_fp16.h>

// EquivariantLieConvLayer on MI355X — memset + 2 plain kernels.
//
//   S[n]   = sum_{e: tgt(e)=n} feat[src(e)]
//   agg[n] = ab*am * bracket(S[n], feat[n])
//   out[n] = feat[n] + agg[n]
//
// upd = [agg, aw*agg] == 0 exactly (antisymmetric C). Dropped (validated r0-4).
//
// Round-5 bug: global_load_lds was issued with a WAVE-UNIFORM global source
// pointer — all lanes fetched the same 16B (LDS dest is base+lane*16, but the
// global src must be per-lane). Fixed: src = row_base + lane*16.
//
// Structure (r4/r5): fp16 feature mirror (fill pre-converts; halves gather
// bytes + working set), gather staged via direct-to-LDS DMA (12 rows x 496B
// per wave, no dest VGPRs -> loads cannot be serialized by regalloc), one
// vmcnt(0) drain, term-parallel in-register bracket with ds_add_f32 scatter.

#define ALG    248
#define ALG4    62     // ALG/4
#define SLOTS   32     // P(deg>32) ~ 1e-11 for Poisson(8)
#define WPB      2     // waves per block
#define TPB    128
#define MAXSL    8     // supports up to 512 base triples (problem has 300)
#define GDEPTH  12     // staged gather rows per node (P(deg>12) ~ 6%)
#define STG    496     // bytes per staged fp16 row (62 x 8B = 31 lanes x 16B)

struct __align__(8) Term { unsigned ijk; float v; };   // i | j<<8 | k<<16

#if defined(__has_builtin)
#if __has_builtin(__builtin_amdgcn_global_load_lds)
#define HAVE_GLL 1
#endif
#endif
#ifndef HAVE_GLL
#define HAVE_GLL 0
#endif

// ---- fill: bucket edges + pack terms + convert feat->fp16 ----------------
__global__ __launch_bounds__(256) void elc_fill(
    const int* __restrict__ ei, int E,
    int* __restrict__ cnt, int* __restrict__ slot,
    const int* __restrict__ ci, const int* __restrict__ cj,
    const int* __restrict__ ck, const float* __restrict__ cv,
    Term* __restrict__ terms, int nnzB,
    const float* __restrict__ feat, uint2* __restrict__ feat16, int N)
{
    const int gt = blockIdx.x * 256 + threadIdx.x;
    const int gs = gridDim.x * 256;

    // A: bucket edges by target
    for (int e = gt; e < E; e += gs) {
        const int t = ei[E + e];
        const int p = atomicAdd(&cnt[t], 1);
        if (p < SLOTS) slot[t * SLOTS + p] = ei[e];
    }
    // B: pack base triples (mirror half implicit in node kernel)
    for (int t = gt; t < MAXSL * 64; t += gs) {
        Term tm; tm.ijk = 0u; tm.v = 0.f;
        if (t < nnzB) {
            tm.ijk = (unsigned)ci[t] | ((unsigned)cj[t] << 8)
                   | ((unsigned)ck[t] << 16);
            tm.v = cv[t];
        }
        terms[t] = tm;
    }
    // C: convert feat -> fp16 (one float4 -> 4 halves per item)
    if (feat16) {
        const int M = N * ALG4;
        const float4* f4 = (const float4*)feat;
        for (int i = gt; i < M; i += gs) {
            const float4 v = f4[i];
            const __half2 lo = __float22half2_rn(make_float2(v.x, v.y));
            const __half2 hi = __float22half2_rn(make_float2(v.z, v.w));
            uint2 o;
            o.x = *(const unsigned*)&lo;
            o.y = *(const unsigned*)&hi;
            feat16[i] = o;
        }
    }
}

// ---- node (fp16 gather via global_load_lds DMA staging) ------------------
__global__ __launch_bounds__(TPB, 4) void elc_node16(
    const float* __restrict__ feat,
    const uint2* __restrict__ feat16,
    const int*   __restrict__ cnt,
    const int*   __restrict__ slot,
    const Term*  __restrict__ terms,
    const float* __restrict__ p_am, const float* __restrict__ p_ab,
    float* __restrict__ out, int N, int nnzB)
{
    // per-wave: 12x496B gather stage (+pad guard) | 496f S/t interleave | 256f ag
    __shared__ __align__(16) char  s_stage[WPB][GDEPTH * STG + 528];
    __shared__ __align__(16) float s_buf[WPB][496];
    __shared__ __align__(16) float s_ag[WPB][256];

    const int tid  = threadIdx.x;
    const int lane = tid & 63;
    const int wave = tid >> 6;

    int nSl = (nnzB + 63) >> 6;
    if (nSl > MAXSL) nSl = MAXSL;

    const int n = blockIdx.x * WPB + wave;
    if (n >= N) return;          // no barriers anywhere: safe

    // independent front loads: metadata, target row (fp32), lane-owned terms
    const int deg = min(cnt[n], SLOTS);
    const int sn  = slot[n * SLOTS + (lane & (SLOTS - 1))];
    const float4* feat4 = (const float4*)feat;
    float4 tgt = make_float4(0.f, 0.f, 0.f, 0.f);
    if (lane < ALG4) tgt = feat4[(size_t)n * ALG4 + lane];

    unsigned tijk[MAXSL];
    float    tval[MAXSL];
#pragma unroll
    for (int sl = 0; sl < MAXSL; ++sl) { tijk[sl] = 0u; tval[sl] = 0.f; }
    for (int sl = 0; sl < nSl; ++sl) {
        const Term tm = terms[(sl << 6) + lane];
        tijk[sl] = tm.ijk; tval[sl] = tm.v;
    }

    char* stg = s_stage[wave];

    // broadcast source ids (all lanes active for shfl)
    int sds[GDEPTH];
#pragma unroll
    for (int d = 0; d < GDEPTH; ++d) sds[d] = __shfl(sn, d);

    float4 acc = make_float4(0.f, 0.f, 0.f, 0.f);

#if HAVE_GLL
    // stage up to 12 rows via direct-to-LDS DMA: 31 lanes x 16B = 496B/row.
    // GLOBAL src is PER-LANE (row_base + lane*16); LDS dest is the wave-
    // uniform row base (HW scatters lane l to base + l*16). No dest VGPRs ->
    // all 12 loads stay in flight; one vmcnt(0) drains them.
    if (lane < 31) {
#pragma unroll
        for (int d = 0; d < GDEPTH; ++d) {
            if (d < deg) {   // wave-uniform branch
                const char* gp = (const char*)(feat16 + (size_t)sds[d] * ALG4)
                               + (size_t)lane * 16;
                __builtin_amdgcn_global_load_lds(
                    (const __attribute__((address_space(1))) void*)(gp),
                    (__attribute__((address_space(3))) void*)(stg + d * STG),
                    16, 0, 0);
            }
        }
    }
    asm volatile("s_waitcnt vmcnt(0)" ::: "memory");
    __builtin_amdgcn_sched_barrier(0);

    // consume staged rows from LDS (8B/lane/row; 2-lane/bank = conflict-free)
    if (lane < ALG4) {
#pragma unroll
        for (int d = 0; d < GDEPTH; ++d) {
            if (d < deg) {
                const uint2 hv = *(const uint2*)(stg + d * STG + lane * 8);
                const float2 lo = __half22float2(*(const __half2*)&hv.x);
                const float2 hi = __half22float2(*(const __half2*)&hv.y);
                acc.x += lo.x; acc.y += lo.y; acc.z += hi.x; acc.w += hi.y;
            }
        }
    }
#else
    // fallback: register gather (r4 path)
    uint2 h[GDEPTH];
#pragma unroll
    for (int d = 0; d < GDEPTH; ++d) {
        h[d] = make_uint2(0u, 0u);
        if (d < deg && lane < ALG4)
            h[d] = feat16[(size_t)sds[d] * ALG4 + lane];
    }
    __builtin_amdgcn_sched_barrier(0);
#pragma unroll
    for (int d = 0; d < GDEPTH; ++d) {
        const float2 lo = __half22float2(*(const __half2*)&h[d].x);
        const float2 hi = __half22float2(*(const __half2*)&h[d].y);
        acc.x += lo.x; acc.y += lo.y; acc.z += hi.x; acc.w += hi.y;
    }
#endif

    for (int d = GDEPTH; d < deg; ++d) {     // rare serial tail (~6%)
        const int sd = __shfl(sn, d);
        if (lane < ALG4) {
            const uint2 hd = feat16[(size_t)sd * ALG4 + lane];
            const float2 lo = __half22float2(*(const __half2*)&hd.x);
            const float2 hi = __half22float2(*(const __half2*)&hd.y);
            acc.x += lo.x; acc.y += lo.y; acc.z += hi.x; acc.w += hi.y;
        }
    }

    // ---- bracket: agg_k = sum_base v*(S_i*t_j - S_j*t_i) ----
    const float cab = (*p_ab) * (*p_am);
    float* sbuf = s_buf[wave];
    float* ag   = s_ag[wave];

    if (lane < ALG4) {   // stage interleaved (S,t): 2x ds_write_b128
        ((float4*)sbuf)[2 * lane]     = make_float4(acc.x, tgt.x, acc.y, tgt.y);
        ((float4*)sbuf)[2 * lane + 1] = make_float4(acc.z, tgt.z, acc.w, tgt.w);
    }
    ((float4*)ag)[lane] = make_float4(0.f, 0.f, 0.f, 0.f);

    auto doSlot = [&](int sl) {
        const unsigned p = tijk[sl];
        const int i2 = (int)((p & 255u) << 1);
        const int j2 = (int)(((p >> 8) & 255u) << 1);
        const float2 a = *(const float2*)(sbuf + i2);   // (S_i, t_i)
        const float2 b = *(const float2*)(sbuf + j2);   // (S_j, t_j)
        float d = a.x * b.y;
        d = fmaf(-b.x, a.y, d);
        atomicAdd(ag + (int)((p >> 16) & 255u), tval[sl] * d);  // ds_add_f32
    };
    if (nSl == 5) {
#pragma unroll
        for (int sl = 0; sl < 5; ++sl) doSlot(sl);
    } else {
        for (int sl = 0; sl < nSl; ++sl) doSlot(sl);
    }

    if (lane < ALG4) {   // out = tgt + cab*ag
        const float4 av = ((const float4*)ag)[lane];
        float4 o;
        o.x = fmaf(cab, av.x, tgt.x);
        o.y = fmaf(cab, av.y, tgt.y);
        o.z = fmaf(cab, av.z, tgt.z);
        o.w = fmaf(cab, av.w, tgt.w);
        ((float4*)(out + (size_t)n * ALG))[lane] = o;
    }
}

// ---- node (f32 fallback, used only if workspace too small) ---------------
__global__ __launch_bounds__(TPB, 5) void elc_node32(
    const float* __restrict__ feat,
    const int*   __restrict__ cnt,
    const int*   __restrict__ slot,
    const Term*  __restrict__ terms,
    const float* __restrict__ p_am, const float* __restrict__ p_ab,
    float* __restrict__ out, int N, int nnzB)
{
    __shared__ __align__(16) float s_buf[WPB][512];
    __shared__ __align__(16) float s_ag[WPB][256];

    const int tid  = threadIdx.x;
    const int lane = tid & 63;
    const int wave = tid >> 6;

    int nSl = (nnzB + 63) >> 6;
    if (nSl > MAXSL) nSl = MAXSL;

    const int n = blockIdx.x * WPB + wave;
    if (n >= N) return;

    const int deg = min(cnt[n], SLOTS);
    const int sn  = slot[n * SLOTS + (lane & (SLOTS - 1))];
    const float4* feat4 = (const float4*)feat;
    float4 tgt = make_float4(0.f, 0.f, 0.f, 0.f);
    if (lane < ALG4) tgt = feat4[(size_t)n * ALG4 + lane];

    unsigned tijk[MAXSL];
    float    tval[MAXSL];
#pragma unroll
    for (int sl = 0; sl < MAXSL; ++sl) { tijk[sl] = 0u; tval[sl] = 0.f; }
    for (int sl = 0; sl < nSl; ++sl) {
        const Term tm = terms[(sl << 6) + lane];
        tijk[sl] = tm.ijk; tval[sl] = tm.v;
    }

    float4 acc = make_float4(0.f, 0.f, 0.f, 0.f);
    for (int d = 0; d < deg; ++d) {
        const int sd = __shfl(sn, d);
        if (lane < ALG4) {
            const float4 fd = feat4[(size_t)sd * ALG4 + lane];
            acc.x += fd.x; acc.y += fd.y; acc.z += fd.z; acc.w += fd.w;
        }
    }

    const float cab = (*p_ab) * (*p_am);
    float* sbuf = s_buf[wave];
    float* ag   = s_ag[wave];

    if (lane < ALG4) {
        ((float4*)sbuf)[2 * lane]     = make_float4(acc.x, tgt.x, acc.y, tgt.y);
        ((float4*)sbuf)[2 * lane + 1] = make_float4(acc.z, tgt.z, acc.w, tgt.w);
    }
    ((float4*)ag)[lane] = make_float4(0.f, 0.f, 0.f, 0.f);

    for (int sl = 0; sl < nSl; ++sl) {
        const unsigned p = tijk[sl];
        const int i2 = (int)((p & 255u) << 1);
        const int j2 = (int)(((p >> 8) & 255u) << 1);
        const float2 a = *(const float2*)(sbuf + i2);
        const float2 b = *(const float2*)(sbuf + j2);
        float d = a.x * b.y;
        d = fmaf(-b.x, a.y, d);
        atomicAdd(ag + (int)((p >> 16) & 255u), tval[sl] * d);
    }

    if (lane < ALG4) {
        const float4 av = ((const float4*)ag)[lane];
        float4 o;
        o.x = fmaf(cab, av.x, tgt.x);
        o.y = fmaf(cab, av.y, tgt.y);
        o.z = fmaf(cab, av.z, tgt.z);
        o.w = fmaf(cab, av.w, tgt.w);
        ((float4*)(out + (size_t)n * ALG))[lane] = o;
    }
}

extern "C" void kernel_launch(void* const* d_in, const int* in_sizes, int n_in,
                              void* d_out, int out_size, void* d_ws, size_t ws_size,
                              hipStream_t stream) {
    const float* feat = (const float*)d_in[0];
    const int*   ei   = (const int*)d_in[1];
    const int*   ci   = (const int*)d_in[2];
    const int*   cj   = (const int*)d_in[3];
    const int*   ck   = (const int*)d_in[4];
    const float* cv   = (const float*)d_in[5];
    const float* p_am = (const float*)d_in[6];
    const float* p_ab = (const float*)d_in[7];
    // d_in[8] (alpha_w), d_in[9] (update_scale) unused: upd == 0 analytically.
    float* out = (float*)d_out;

    const int N    = in_sizes[0] / ALG;   // 20000
    const int E    = in_sizes[1] / 2;     // 160000
    const int nnz  = in_sizes[5];         // 600
    const int nnzB = nnz >> 1;            // base triples (mirror half implicit)

    // ---- workspace layout ----
    // cnt: N ints | slot: N*32 ints | terms: 512*8B | feat16: N*62*8B
    char* w = (char*)d_ws;
    int*  cnt   = (int*)w;               w += ((size_t)N * 4 + 255) & ~255ull;
    int*  slot  = (int*)w;               w += ((size_t)N * SLOTS * 4 + 255) & ~255ull;
    Term* terms = (Term*)w;              w += ((size_t)MAXSL * 64 * 8 + 255) & ~255ull;
    uint2* feat16 = (uint2*)w;           w += (size_t)N * ALG4 * 8;
    const bool use16 = ((size_t)(w - (char*)d_ws) <= ws_size);

    hipMemsetAsync(cnt, 0, (size_t)N * sizeof(int), stream);
    elc_fill<<<1024, 256, 0, stream>>>(ei, E, cnt, slot, ci, cj, ck, cv,
                                       terms, nnzB, feat,
                                       use16 ? feat16 : (uint2*)nullptr, N);

    const int nblk = (N + WPB - 1) / WPB;   // 10000
    if (use16)
        elc_node16<<<nblk, TPB, 0, stream>>>(feat, feat16, cnt, slot, terms,
                                             p_am, p_ab, out, N, nnzB);
    else
        elc_node32<<<nblk, TPB, 0, stream>>>(feat, cnt, slot, terms,
                                             p_am, p_ab, out, N, nnzB);
}

// Round 8
// 147.400 us; speedup vs baseline: 1.0151x; 1.0151x over previous
//
#include <hip/hip_runtime.h>
#include <hip/hip_fp16.h>

// EquivariantLieConvLayer on MI355X — memset + fill + node (3 ops).
//
//   S[n]   = sum_{e: tgt(e)=n} feat[src(e)]
//   agg[n] = ab*am * bracket(S[n], feat[n])
//   out[n] = feat[n] + agg[n]
//
// upd = [agg, aw*agg] == 0 exactly (antisymmetric C). Dropped (validated r0-6).
//
// r7 lesson (FAILED): cnt cannot live in d_out — harness zeroes d_out only
// before the first launch; graph replays see stale values. cnt is a
// workspace array zeroed by an explicit memset every launch.
//
// Node = r6 DMA gather + r7 LDS aliasing, first time at HIGH occupancy:
//   - gather staged via global_load_lds (per-lane global src, wave-uniform
//     LDS dest): 12 rows x 496B, no dest VGPRs -> 12 loads in flight/wave.
//   - bracket scratch (sbuf 496f + ag 256f = 3KB) aliased into the stage
//     buffer after consumption -> 11.9KB LDS/block -> 13 blocks/CU (~81%).
//   - fp16 feature mirror for gather + target (err ~5e-3 << 3.04 threshold).

#define ALG    248
#define ALG4    62     // ALG/4
#define SLOTS   32     // P(deg>32) ~ 1e-11 for Poisson(8)
#define WPB      2     // waves per block
#define TPB    128
#define MAXSL    8     // supports up to 512 base triples (problem has 300)
#define GDEPTH  12     // staged gather rows per node (P(deg>12) ~ 6%)
#define STG    496     // bytes per staged fp16 row (62 x 8B = 31 lanes x 16B)
#define WLDS  (GDEPTH * STG)   // per-wave LDS (5952 B); sbuf+ag alias into it

struct __align__(8) Term { unsigned ijk; float v; };   // i | j<<8 | k<<16

#if defined(__has_builtin)
#if __has_builtin(__builtin_amdgcn_global_load_lds)
#define HAVE_GLL 1
#endif
#endif
#ifndef HAVE_GLL
#define HAVE_GLL 0
#endif

// ---- fill: bucket edges + pack terms + fp16 convert ----------------------
__global__ __launch_bounds__(256) void elc_fill(
    const int* __restrict__ ei, int E,
    int* __restrict__ cnt, int* __restrict__ slot,
    const int* __restrict__ ci, const int* __restrict__ cj,
    const int* __restrict__ ck, const float* __restrict__ cv,
    Term* __restrict__ terms, int nnzB,
    const float* __restrict__ feat, uint2* __restrict__ feat16, int N)
{
    const int gt = blockIdx.x * 256 + threadIdx.x;
    const int gs = gridDim.x * 256;

    // A: bucket edges by target (cnt zeroed by the preceding memset)
    for (int e = gt; e < E; e += gs) {
        const int t = ei[E + e];
        const int p = atomicAdd(&cnt[t], 1);
        if (p < SLOTS) slot[t * SLOTS + p] = ei[e];
    }
    // B: pack base triples (mirror half implicit in node kernel)
    for (int t = gt; t < MAXSL * 64; t += gs) {
        Term tm; tm.ijk = 0u; tm.v = 0.f;
        if (t < nnzB) {
            tm.ijk = (unsigned)ci[t] | ((unsigned)cj[t] << 8)
                   | ((unsigned)ck[t] << 16);
            tm.v = cv[t];
        }
        terms[t] = tm;
    }
    // C: convert feat -> fp16 mirror (one float4 -> 4 halves per item)
    if (feat16) {
        const int M = N * ALG4;
        const float4* f4 = (const float4*)feat;
        for (int i = gt; i < M; i += gs) {
            const float4 v = f4[i];
            const __half2 lo = __float22half2_rn(make_float2(v.x, v.y));
            const __half2 hi = __float22half2_rn(make_float2(v.z, v.w));
            uint2 o;
            o.x = *(const unsigned*)&lo;
            o.y = *(const unsigned*)&hi;
            feat16[i] = o;
        }
    }
}

// ---- node: fp16 DMA gather, aliased LDS, high occupancy ------------------
__global__ __launch_bounds__(TPB, 6) void elc_node16(
    const uint2* __restrict__ feat16,
    const int*   __restrict__ cnt,
    const int*   __restrict__ slot,
    const Term*  __restrict__ terms,
    const float* __restrict__ p_am, const float* __restrict__ p_ab,
    float* __restrict__ out, int N, int nnzB)
{
    // per-wave 5952B: [0,5952) gather stage; after consumption the first
    // 3008B are reused as sbuf (496 f) + ag (256 f).
    __shared__ __align__(16) char s_lds[WPB][WLDS];

    const int tid  = threadIdx.x;
    const int lane = tid & 63;
    const int wave = tid >> 6;

    int nSl = (nnzB + 63) >> 6;
    if (nSl > MAXSL) nSl = MAXSL;

    const int n = blockIdx.x * WPB + wave;
    if (n >= N) return;          // no barriers anywhere: safe

    // front loads (independent): cnt, slot row, tgt fp16, terms
    const int deg = min(max(cnt[n], 0), SLOTS);
    const int sn  = slot[n * SLOTS + (lane & (SLOTS - 1))];

    uint2 th = make_uint2(0u, 0u);
    if (lane < ALG4) th = feat16[(size_t)n * ALG4 + lane];

    unsigned tijk[MAXSL];
    float    tval[MAXSL];
#pragma unroll
    for (int sl = 0; sl < MAXSL; ++sl) { tijk[sl] = 0u; tval[sl] = 0.f; }
    for (int sl = 0; sl < nSl; ++sl) {
        const Term tm = terms[(sl << 6) + lane];
        tijk[sl] = tm.ijk; tval[sl] = tm.v;
    }

    char* stg = s_lds[wave];

    // broadcast source ids (all lanes active for shfl)
    int sds[GDEPTH];
#pragma unroll
    for (int d = 0; d < GDEPTH; ++d) sds[d] = __shfl(sn, d);

    // decode fp16 target row
    float4 tgt;
    {
        const float2 lo = __half22float2(*(const __half2*)&th.x);
        const float2 hi = __half22float2(*(const __half2*)&th.y);
        tgt = make_float4(lo.x, lo.y, hi.x, hi.y);
    }

    float4 acc = make_float4(0.f, 0.f, 0.f, 0.f);

#if HAVE_GLL
    // stage up to 12 rows via direct-to-LDS DMA: 31 lanes x 16B = 496B/row.
    // GLOBAL src is PER-LANE (row_base + lane*16); LDS dest is the wave-
    // uniform row base (HW scatters lane l to base + l*16). No dest VGPRs ->
    // all loads stay in flight; one vmcnt(0) drains them.
    if (lane < 31) {
#pragma unroll
        for (int d = 0; d < GDEPTH; ++d) {
            if (d < deg) {   // wave-uniform branch
                const char* gp = (const char*)(feat16 + (size_t)sds[d] * ALG4)
                               + (size_t)lane * 16;
                __builtin_amdgcn_global_load_lds(
                    (const __attribute__((address_space(1))) void*)(gp),
                    (__attribute__((address_space(3))) void*)(stg + d * STG),
                    16, 0, 0);
            }
        }
    }
    asm volatile("s_waitcnt vmcnt(0)" ::: "memory");
    __builtin_amdgcn_sched_barrier(0);

    // consume staged rows from LDS (8B/lane/row; 2-lane/bank = conflict-free)
    if (lane < ALG4) {
#pragma unroll
        for (int d = 0; d < GDEPTH; ++d) {
            if (d < deg) {
                const uint2 hv = *(const uint2*)(stg + d * STG + lane * 8);
                const float2 lo = __half22float2(*(const __half2*)&hv.x);
                const float2 hi = __half22float2(*(const __half2*)&hv.y);
                acc.x += lo.x; acc.y += lo.y; acc.z += hi.x; acc.w += hi.y;
            }
        }
    }
#else
    uint2 h[GDEPTH];
#pragma unroll
    for (int d = 0; d < GDEPTH; ++d) {
        h[d] = make_uint2(0u, 0u);
        if (d < deg && lane < ALG4)
            h[d] = feat16[(size_t)sds[d] * ALG4 + lane];
    }
    __builtin_amdgcn_sched_barrier(0);
#pragma unroll
    for (int d = 0; d < GDEPTH; ++d) {
        const float2 lo = __half22float2(*(const __half2*)&h[d].x);
        const float2 hi = __half22float2(*(const __half2*)&h[d].y);
        acc.x += lo.x; acc.y += lo.y; acc.z += hi.x; acc.w += hi.y;
    }
#endif

    for (int d = GDEPTH; d < deg; ++d) {     // rare serial tail (~6%)
        const int sd = __shfl(sn, d);
        if (lane < ALG4) {
            const uint2 hd = feat16[(size_t)sd * ALG4 + lane];
            const float2 lo = __half22float2(*(const __half2*)&hd.x);
            const float2 hi = __half22float2(*(const __half2*)&hd.y);
            acc.x += lo.x; acc.y += lo.y; acc.z += hi.x; acc.w += hi.y;
        }
    }

    // ---- bracket (stage buffer dead now; alias sbuf/ag into it) ----
    __builtin_amdgcn_sched_barrier(0);       // keep ds_writes below the reads above
    const float cab = (*p_ab) * (*p_am);
    float* sbuf = (float*)stg;               // 496 floats, interleaved (S_m, t_m)
    float* ag   = (float*)(stg + 1984);      // 256 floats

    if (lane < ALG4) {   // stage interleaved (S,t): 2x ds_write_b128
        ((float4*)sbuf)[2 * lane]     = make_float4(acc.x, tgt.x, acc.y, tgt.y);
        ((float4*)sbuf)[2 * lane + 1] = make_float4(acc.z, tgt.z, acc.w, tgt.w);
    }
    ((float4*)ag)[lane] = make_float4(0.f, 0.f, 0.f, 0.f);

    auto doSlot = [&](int sl) {
        const unsigned p = tijk[sl];
        const int i2 = (int)((p & 255u) << 1);
        const int j2 = (int)(((p >> 8) & 255u) << 1);
        const float2 a = *(const float2*)(sbuf + i2);   // (S_i, t_i)
        const float2 b = *(const float2*)(sbuf + j2);   // (S_j, t_j)
        float d = a.x * b.y;
        d = fmaf(-b.x, a.y, d);
        atomicAdd(ag + (int)((p >> 16) & 255u), tval[sl] * d);  // ds_add_f32
    };
    if (nSl == 5) {
#pragma unroll
        for (int sl = 0; sl < 5; ++sl) doSlot(sl);
    } else {
        for (int sl = 0; sl < nSl; ++sl) doSlot(sl);
    }

    if (lane < ALG4) {   // out = tgt + cab*ag
        const float4 av = ((const float4*)ag)[lane];
        float4 o;
        o.x = fmaf(cab, av.x, tgt.x);
        o.y = fmaf(cab, av.y, tgt.y);
        o.z = fmaf(cab, av.z, tgt.z);
        o.w = fmaf(cab, av.w, tgt.w);
        ((float4*)(out + (size_t)n * ALG))[lane] = o;
    }
}

// ---- node (f32 fallback, used only if workspace too small) ---------------
__global__ __launch_bounds__(TPB, 5) void elc_node32(
    const float* __restrict__ feat,
    const int*   __restrict__ cnt,
    const int*   __restrict__ slot,
    const Term*  __restrict__ terms,
    const float* __restrict__ p_am, const float* __restrict__ p_ab,
    float* __restrict__ out, int N, int nnzB)
{
    __shared__ __align__(16) float s_buf[WPB][512];
    __shared__ __align__(16) float s_ag[WPB][256];

    const int tid  = threadIdx.x;
    const int lane = tid & 63;
    const int wave = tid >> 6;

    int nSl = (nnzB + 63) >> 6;
    if (nSl > MAXSL) nSl = MAXSL;

    const int n = blockIdx.x * WPB + wave;
    if (n >= N) return;

    const int deg = min(max(cnt[n], 0), SLOTS);
    const int sn  = slot[n * SLOTS + (lane & (SLOTS - 1))];
    const float4* feat4 = (const float4*)feat;
    float4 tgt = make_float4(0.f, 0.f, 0.f, 0.f);
    if (lane < ALG4) tgt = feat4[(size_t)n * ALG4 + lane];

    unsigned tijk[MAXSL];
    float    tval[MAXSL];
#pragma unroll
    for (int sl = 0; sl < MAXSL; ++sl) { tijk[sl] = 0u; tval[sl] = 0.f; }
    for (int sl = 0; sl < nSl; ++sl) {
        const Term tm = terms[(sl << 6) + lane];
        tijk[sl] = tm.ijk; tval[sl] = tm.v;
    }

    float4 acc = make_float4(0.f, 0.f, 0.f, 0.f);
    for (int d = 0; d < deg; ++d) {
        const int sd = __shfl(sn, d);
        if (lane < ALG4) {
            const float4 fd = feat4[(size_t)sd * ALG4 + lane];
            acc.x += fd.x; acc.y += fd.y; acc.z += fd.z; acc.w += fd.w;
        }
    }

    const float cab = (*p_ab) * (*p_am);
    float* sbuf = s_buf[wave];
    float* ag   = s_ag[wave];

    if (lane < ALG4) {
        ((float4*)sbuf)[2 * lane]     = make_float4(acc.x, tgt.x, acc.y, tgt.y);
        ((float4*)sbuf)[2 * lane + 1] = make_float4(acc.z, tgt.z, acc.w, tgt.w);
    }
    ((float4*)ag)[lane] = make_float4(0.f, 0.f, 0.f, 0.f);

    for (int sl = 0; sl < nSl; ++sl) {
        const unsigned p = tijk[sl];
        const int i2 = (int)((p & 255u) << 1);
        const int j2 = (int)(((p >> 8) & 255u) << 1);
        const float2 a = *(const float2*)(sbuf + i2);
        const float2 b = *(const float2*)(sbuf + j2);
        float d = a.x * b.y;
        d = fmaf(-b.x, a.y, d);
        atomicAdd(ag + (int)((p >> 16) & 255u), tval[sl] * d);
    }

    if (lane < ALG4) {
        const float4 av = ((const float4*)ag)[lane];
        float4 o;
        o.x = fmaf(cab, av.x, tgt.x);
        o.y = fmaf(cab, av.y, tgt.y);
        o.z = fmaf(cab, av.z, tgt.z);
        o.w = fmaf(cab, av.w, tgt.w);
        ((float4*)(out + (size_t)n * ALG))[lane] = o;
    }
}

extern "C" void kernel_launch(void* const* d_in, const int* in_sizes, int n_in,
                              void* d_out, int out_size, void* d_ws, size_t ws_size,
                              hipStream_t stream) {
    const float* feat = (const float*)d_in[0];
    const int*   ei   = (const int*)d_in[1];
    const int*   ci   = (const int*)d_in[2];
    const int*   cj   = (const int*)d_in[3];
    const int*   ck   = (const int*)d_in[4];
    const float* cv   = (const float*)d_in[5];
    const float* p_am = (const float*)d_in[6];
    const float* p_ab = (const float*)d_in[7];
    // d_in[8] (alpha_w), d_in[9] (update_scale) unused: upd == 0 analytically.
    float* out = (float*)d_out;

    const int N    = in_sizes[0] / ALG;   // 20000
    const int E    = in_sizes[1] / 2;     // 160000
    const int nnz  = in_sizes[5];         // 600
    const int nnzB = nnz >> 1;            // base triples (mirror half implicit)

    // ---- workspace layout: cnt | slot | terms | feat16 (~12.6 MB) ----
    char* w = (char*)d_ws;
    int*  cnt   = (int*)w;               w += ((size_t)N * 4 + 255) & ~255ull;
    int*  slot  = (int*)w;               w += ((size_t)N * SLOTS * 4 + 255) & ~255ull;
    Term* terms = (Term*)w;              w += ((size_t)MAXSL * 64 * 8 + 255) & ~255ull;
    uint2* feat16 = (uint2*)w;           w += (size_t)N * ALG4 * 8;
    const bool use16 = ((size_t)(w - (char*)d_ws) <= ws_size);

    hipMemsetAsync(cnt, 0, (size_t)N * sizeof(int), stream);
    elc_fill<<<1024, 256, 0, stream>>>(ei, E, cnt, slot, ci, cj, ck, cv,
                                       terms, nnzB, feat,
                                       use16 ? feat16 : (uint2*)nullptr, N);

    const int nblk = (N + WPB - 1) / WPB;   // 10000
    if (use16)
        elc_node16<<<nblk, TPB, 0, stream>>>(feat16, cnt, slot, terms,
                                             p_am, p_ab, out, N, nnzB);
    else
        elc_node32<<<nblk, TPB, 0, stream>>>(feat, cnt, slot, terms,
                                             p_am, p_ab, out, N, nnzB);
}

// Round 9
// 141.359 us; speedup vs baseline: 1.0585x; 1.0427x over previous
//
#include <hip/hip_runtime.h>
#include <hip/hip_fp16.h>

// EquivariantLieConvLayer on MI355X — memset(0xFF) + fill + node (3 ops).
//
//   S[n]   = sum_{e: tgt(e)=n} feat[src(e)]
//   agg[n] = ab*am * bracket(S[n], feat[n])
//   out[n] = feat[n] + agg[n]
//
// upd = [agg, aw*agg] == 0 exactly (antisymmetric C). Dropped (validated r0-8).
//
// r8 lesson: six node variants (bytes 2x, occupancy 2x, MLP 6x) all land at
// 49-54us with no saturated counter -> latency-CHAIN bound. This round
// shortens the chain: cnt is never read by node. The cnt+slot region is
// memset to 0xFF; fill counts from -1 (q = old+1); node gets deg by BALLOT
// over slot sentinels (slot != -1). Chain: slot -> gather (was cnt -> slot
// -> gather). deg>12 tail is now a BATCHED 8-deep issue (was serial loads),
// serial only past 20 (P ~ 1e-4).

#define ALG    248
#define ALG4    62     // ALG/4
#define SLOTS   32     // P(deg>32) ~ 1e-11 for Poisson(8)
#define WPB      2     // waves per block
#define TPB    128
#define MAXSL    8     // supports up to 512 base triples (problem has 300)

struct __align__(8) Term { unsigned ijk; float v; };   // i | j<<8 | k<<16

// ---- fill: bucket edges (cnt from -1) + pack terms + fp16 convert --------
__global__ __launch_bounds__(256) void elc_fill(
    const int* __restrict__ ei, int E,
    int* __restrict__ cnt, int* __restrict__ slot,
    const int* __restrict__ ci, const int* __restrict__ cj,
    const int* __restrict__ ck, const float* __restrict__ cv,
    Term* __restrict__ terms, int nnzB,
    const float* __restrict__ feat, uint2* __restrict__ feat16, int N)
{
    const int gt = blockIdx.x * 256 + threadIdx.x;
    const int gs = gridDim.x * 256;

    // A: bucket edges by target. cnt memset to 0xFF (= -1): q = old+1 is the
    // slot index. slot also 0xFF -> unwritten entries read as -1 (sentinel).
    for (int e = gt; e < E; e += gs) {
        const int t = ei[E + e];
        const int q = atomicAdd(&cnt[t], 1) + 1;
        if (q >= 0 && q < SLOTS) slot[t * SLOTS + q] = ei[e];
    }
    // B: pack base triples (mirror half implicit in node kernel)
    for (int t = gt; t < MAXSL * 64; t += gs) {
        Term tm; tm.ijk = 0u; tm.v = 0.f;
        if (t < nnzB) {
            tm.ijk = (unsigned)ci[t] | ((unsigned)cj[t] << 8)
                   | ((unsigned)ck[t] << 16);
            tm.v = cv[t];
        }
        terms[t] = tm;
    }
    // C: convert feat -> fp16 mirror (one float4 -> 4 halves per item)
    if (feat16) {
        const int M = N * ALG4;
        const float4* f4 = (const float4*)feat;
        for (int i = gt; i < M; i += gs) {
            const float4 v = f4[i];
            const __half2 lo = __float22half2_rn(make_float2(v.x, v.y));
            const __half2 hi = __float22half2_rn(make_float2(v.z, v.w));
            uint2 o;
            o.x = *(const unsigned*)&lo;
            o.y = *(const unsigned*)&hi;
            feat16[i] = o;
        }
    }
}

// ---- node: fp16 register gather, sentinel-deg, batched tail --------------
__global__ __launch_bounds__(TPB, 6) void elc_node16(
    const uint2* __restrict__ feat16,
    const int*   __restrict__ slot,
    const Term*  __restrict__ terms,
    const float* __restrict__ p_am, const float* __restrict__ p_ab,
    float* __restrict__ out, int N, int nnzB)
{
    __shared__ __align__(16) float s_buf[WPB][512];  // interleaved: buf[2m]=S_m, buf[2m+1]=t_m
    __shared__ __align__(16) float s_ag[WPB][256];   // wave-private bracket accumulator

    const int tid  = threadIdx.x;
    const int lane = tid & 63;
    const int wave = tid >> 6;

    int nSl = (nnzB + 63) >> 6;
    if (nSl > MAXSL) nSl = MAXSL;

    const int n = blockIdx.x * WPB + wave;
    if (n >= N) return;          // no barriers anywhere: safe

    // front loads (independent): slot row, tgt fp16, terms.
    // deg comes from slot sentinels — no cnt load on the chain.
    const int sn = slot[n * SLOTS + (lane & (SLOTS - 1))];

    uint2 th = make_uint2(0u, 0u);
    if (lane < ALG4) th = feat16[(size_t)n * ALG4 + lane];

    unsigned tijk[MAXSL];
    float    tval[MAXSL];
#pragma unroll
    for (int sl = 0; sl < MAXSL; ++sl) { tijk[sl] = 0u; tval[sl] = 0.f; }
    for (int sl = 0; sl < nSl; ++sl) {
        const Term tm = terms[(sl << 6) + lane];
        tijk[sl] = tm.ijk; tval[sl] = tm.v;
    }

    // deg = number of valid slots (fill writes them contiguously from 0)
    const unsigned long long vm =
        __ballot(lane < SLOTS && sn >= 0);
    const int deg = __popcll(vm);

    // broadcast source ids
    int sds[12];
#pragma unroll
    for (int d = 0; d < 12; ++d) sds[d] = __shfl(sn, d);

    // decode fp16 target row
    float4 tgt;
    {
        const float2 lo = __half22float2(*(const __half2*)&th.x);
        const float2 hi = __half22float2(*(const __half2*)&th.y);
        tgt = make_float4(lo.x, lo.y, hi.x, hi.y);
    }

    // gather batch 1: issue all 12, fence, consume
    uint2 h[12];
#pragma unroll
    for (int d = 0; d < 12; ++d) {
        h[d] = make_uint2(0u, 0u);
        if (d < deg && lane < ALG4)
            h[d] = feat16[(size_t)sds[d] * ALG4 + lane];
    }
    __builtin_amdgcn_sched_barrier(0);

    float4 acc = make_float4(0.f, 0.f, 0.f, 0.f);
#pragma unroll
    for (int d = 0; d < 12; ++d) {
        const float2 lo = __half22float2(*(const __half2*)&h[d].x);
        const float2 hi = __half22float2(*(const __half2*)&h[d].y);
        acc.x += lo.x; acc.y += lo.y; acc.z += hi.x; acc.w += hi.y;
    }

    if (deg > 12) {          // wave-uniform, ~6% of waves: batched tail of 8
        uint2 g[8];
#pragma unroll
        for (int d = 0; d < 8; ++d) {
            g[d] = make_uint2(0u, 0u);
            const int sd = __shfl(sn, d + 12);
            if (d + 12 < deg && lane < ALG4)
                g[d] = feat16[(size_t)sd * ALG4 + lane];
        }
        __builtin_amdgcn_sched_barrier(0);
#pragma unroll
        for (int d = 0; d < 8; ++d) {
            const float2 lo = __half22float2(*(const __half2*)&g[d].x);
            const float2 hi = __half22float2(*(const __half2*)&g[d].y);
            acc.x += lo.x; acc.y += lo.y; acc.z += hi.x; acc.w += hi.y;
        }
        for (int d = 20; d < deg; ++d) {     // P(deg>20) ~ 1e-4
            const int sd = __shfl(sn, d);
            if (lane < ALG4) {
                const uint2 hd = feat16[(size_t)sd * ALG4 + lane];
                const float2 lo = __half22float2(*(const __half2*)&hd.x);
                const float2 hi = __half22float2(*(const __half2*)&hd.y);
                acc.x += lo.x; acc.y += lo.y; acc.z += hi.x; acc.w += hi.y;
            }
        }
    }

    // ---- bracket: agg_k = sum_base v*(S_i*t_j - S_j*t_i) ----
    const float cab = (*p_ab) * (*p_am);
    float* sbuf = s_buf[wave];
    float* ag   = s_ag[wave];

    if (lane < ALG4) {   // stage interleaved (S,t): 2x ds_write_b128
        ((float4*)sbuf)[2 * lane]     = make_float4(acc.x, tgt.x, acc.y, tgt.y);
        ((float4*)sbuf)[2 * lane + 1] = make_float4(acc.z, tgt.z, acc.w, tgt.w);
    }
    ((float4*)ag)[lane] = make_float4(0.f, 0.f, 0.f, 0.f);

    auto doSlot = [&](int sl) {
        const unsigned p = tijk[sl];
        const int i2 = (int)((p & 255u) << 1);
        const int j2 = (int)(((p >> 8) & 255u) << 1);
        const float2 a = *(const float2*)(sbuf + i2);   // (S_i, t_i)
        const float2 b = *(const float2*)(sbuf + j2);   // (S_j, t_j)
        float d = a.x * b.y;
        d = fmaf(-b.x, a.y, d);
        atomicAdd(ag + (int)((p >> 16) & 255u), tval[sl] * d);  // ds_add_f32
    };
    if (nSl == 5) {
#pragma unroll
        for (int sl = 0; sl < 5; ++sl) doSlot(sl);
    } else {
        for (int sl = 0; sl < nSl; ++sl) doSlot(sl);
    }

    if (lane < ALG4) {   // out = tgt + cab*ag
        const float4 av = ((const float4*)ag)[lane];
        float4 o;
        o.x = fmaf(cab, av.x, tgt.x);
        o.y = fmaf(cab, av.y, tgt.y);
        o.z = fmaf(cab, av.z, tgt.z);
        o.w = fmaf(cab, av.w, tgt.w);
        ((float4*)(out + (size_t)n * ALG))[lane] = o;
    }
}

// ---- node (f32 fallback, used only if workspace too small) ---------------
__global__ __launch_bounds__(TPB, 5) void elc_node32(
    const float* __restrict__ feat,
    const int*   __restrict__ slot,
    const Term*  __restrict__ terms,
    const float* __restrict__ p_am, const float* __restrict__ p_ab,
    float* __restrict__ out, int N, int nnzB)
{
    __shared__ __align__(16) float s_buf[WPB][512];
    __shared__ __align__(16) float s_ag[WPB][256];

    const int tid  = threadIdx.x;
    const int lane = tid & 63;
    const int wave = tid >> 6;

    int nSl = (nnzB + 63) >> 6;
    if (nSl > MAXSL) nSl = MAXSL;

    const int n = blockIdx.x * WPB + wave;
    if (n >= N) return;

    const int sn = slot[n * SLOTS + (lane & (SLOTS - 1))];
    const unsigned long long vm = __ballot(lane < SLOTS && sn >= 0);
    const int deg = __popcll(vm);

    const float4* feat4 = (const float4*)feat;
    float4 tgt = make_float4(0.f, 0.f, 0.f, 0.f);
    if (lane < ALG4) tgt = feat4[(size_t)n * ALG4 + lane];

    unsigned tijk[MAXSL];
    float    tval[MAXSL];
#pragma unroll
    for (int sl = 0; sl < MAXSL; ++sl) { tijk[sl] = 0u; tval[sl] = 0.f; }
    for (int sl = 0; sl < nSl; ++sl) {
        const Term tm = terms[(sl << 6) + lane];
        tijk[sl] = tm.ijk; tval[sl] = tm.v;
    }

    float4 acc = make_float4(0.f, 0.f, 0.f, 0.f);
    for (int d = 0; d < deg; ++d) {
        const int sd = __shfl(sn, d);
        if (lane < ALG4) {
            const float4 fd = feat4[(size_t)sd * ALG4 + lane];
            acc.x += fd.x; acc.y += fd.y; acc.z += fd.z; acc.w += fd.w;
        }
    }

    const float cab = (*p_ab) * (*p_am);
    float* sbuf = s_buf[wave];
    float* ag   = s_ag[wave];

    if (lane < ALG4) {
        ((float4*)sbuf)[2 * lane]     = make_float4(acc.x, tgt.x, acc.y, tgt.y);
        ((float4*)sbuf)[2 * lane + 1] = make_float4(acc.z, tgt.z, acc.w, tgt.w);
    }
    ((float4*)ag)[lane] = make_float4(0.f, 0.f, 0.f, 0.f);

    for (int sl = 0; sl < nSl; ++sl) {
        const unsigned p = tijk[sl];
        const int i2 = (int)((p & 255u) << 1);
        const int j2 = (int)(((p >> 8) & 255u) << 1);
        const float2 a = *(const float2*)(sbuf + i2);
        const float2 b = *(const float2*)(sbuf + j2);
        float d = a.x * b.y;
        d = fmaf(-b.x, a.y, d);
        atomicAdd(ag + (int)((p >> 16) & 255u), tval[sl] * d);
    }

    if (lane < ALG4) {
        const float4 av = ((const float4*)ag)[lane];
        float4 o;
        o.x = fmaf(cab, av.x, tgt.x);
        o.y = fmaf(cab, av.y, tgt.y);
        o.z = fmaf(cab, av.z, tgt.z);
        o.w = fmaf(cab, av.w, tgt.w);
        ((float4*)(out + (size_t)n * ALG))[lane] = o;
    }
}

extern "C" void kernel_launch(void* const* d_in, const int* in_sizes, int n_in,
                              void* d_out, int out_size, void* d_ws, size_t ws_size,
                              hipStream_t stream) {
    const float* feat = (const float*)d_in[0];
    const int*   ei   = (const int*)d_in[1];
    const int*   ci   = (const int*)d_in[2];
    const int*   cj   = (const int*)d_in[3];
    const int*   ck   = (const int*)d_in[4];
    const float* cv   = (const float*)d_in[5];
    const float* p_am = (const float*)d_in[6];
    const float* p_ab = (const float*)d_in[7];
    // d_in[8] (alpha_w), d_in[9] (update_scale) unused: upd == 0 analytically.
    float* out = (float*)d_out;

    const int N    = in_sizes[0] / ALG;   // 20000
    const int E    = in_sizes[1] / 2;     // 160000
    const int nnz  = in_sizes[5];         // 600
    const int nnzB = nnz >> 1;            // base triples (mirror half implicit)

    // ---- workspace layout: [cnt | slot] (one 0xFF memset) | terms | feat16
    char* w = (char*)d_ws;
    int*  cnt   = (int*)w;               // N ints, init -1
    int*  slot  = cnt + N;               // N*SLOTS ints, init -1 (sentinel)
    w += ((size_t)N * (1 + SLOTS) * 4 + 255) & ~255ull;
    Term* terms = (Term*)w;              w += ((size_t)MAXSL * 64 * 8 + 255) & ~255ull;
    uint2* feat16 = (uint2*)w;           w += (size_t)N * ALG4 * 8;
    const bool use16 = ((size_t)(w - (char*)d_ws) <= ws_size);

    hipMemsetAsync(cnt, 0xFF, (size_t)N * (1 + SLOTS) * sizeof(int), stream);
    elc_fill<<<2048, 256, 0, stream>>>(ei, E, cnt, slot, ci, cj, ck, cv,
                                       terms, nnzB, feat,
                                       use16 ? feat16 : (uint2*)nullptr, N);

    const int nblk = (N + WPB - 1) / WPB;   // 10000
    if (use16)
        elc_node16<<<nblk, TPB, 0, stream>>>(feat16, slot, terms,
                                             p_am, p_ab, out, N, nnzB);
    else
        elc_node32<<<nblk, TPB, 0, stream>>>(feat, slot, terms,
                                             p_am, p_ab, out, N, nnzB);
}